// Round 4
// baseline (453.582 us; speedup 1.0000x reference)
//
#include <hip/hip_runtime.h>

// x: (32, 2, 513, 2048) fp32. Row = (b, f): 2048 elems.
// noise = mean of 32 smallest mag^2; out[b,0] = relu(mag-noise)*cos(ph),
// out[b,1] = relu(mag-noise)*sin(ph).
//
// One wave per row. The WHOLE row (mag + phase, 16 KB) is loaded up-front
// and pinned in VGPRs with inline-asm value barriers ("+v") -- the compiler
// has twice chosen to rematerialize these loads (VGPR_Count 32/40) and run
// the 16-pass search against L1/L2 instead of registers; asm that may have
// modified a value cannot be re-loaded from memory, so residency is forced.
//  - 16 dwordx4 loads issue back-to-back (16 KB MLP/wave), one drain point
//  - search + ssq + epilogue then run with ZERO memory dependence
// k=32 order statistic via 16-step MSB-first binary search on the bit
// pattern of |mag| (uint order == float order for non-negative floats).
// Wave-wide count per step via __ballot + scalar popcount, 4 independent
// accumulators to shorten the per-step scalar dependency chain.

#define NROWS      16416          // 32*513
#define HALF_PLANE (513 * 2048)   // stride between channel 0 and 1
#define LOWBIT     15             // search bits 30..LOWBIT (16 iterations)

typedef float v4f __attribute__((ext_vector_type(4)));

__global__ __launch_bounds__(256) void spectral_sub_kernel(
    const float* __restrict__ x, float* __restrict__ out) {
  const int lane = threadIdx.x & 63;
  const int waveInBlock = threadIdx.x >> 6;
  const int row = blockIdx.x * 4 + waveInBlock;   // grid covers exactly NROWS
  if (row >= NROWS) return;

  const int b = row / 513;
  const int f = row - b * 513;
  const size_t base = ((size_t)b * 2 * 513 + (size_t)f) * 2048;

  const float* magp = x + base;
  const float* php  = x + base + HALF_PLANE;

  // ---- load full row (mag + phase) into named scalars ----
  float mg[32], ph[32];
#pragma unroll
  for (int j = 0; j < 8; ++j) {
    const v4f v = *(const v4f*)(magp + j * 256 + lane * 4);
    mg[4 * j + 0] = v.x; mg[4 * j + 1] = v.y;
    mg[4 * j + 2] = v.z; mg[4 * j + 3] = v.w;
  }
#pragma unroll
  for (int j = 0; j < 8; ++j) {
    const v4f v = *(const v4f*)(php + j * 256 + lane * 4);
    ph[4 * j + 0] = v.x; ph[4 * j + 1] = v.y;
    ph[4 * j + 2] = v.z; ph[4 * j + 3] = v.w;
  }
  // ---- pin in registers: a value inline asm may have modified cannot be
  // rematerialized by re-loading from x. Zero instructions emitted.
#pragma unroll
  for (int i = 0; i < 32; ++i) {
    asm volatile("" : "+v"(mg[i]));
    asm volatile("" : "+v"(ph[i]));
  }

  // ---- binary search for the 32nd smallest |mag| (bit pattern T) ----
  // Invariant: count(|m| < T) < 32. Pure register/ballot/scalar loop.
  unsigned T = 0;
#pragma unroll 1
  for (int bit = 30; bit >= LOWBIT; --bit) {
    const unsigned cand = T | (1u << bit);
    const float candf = __uint_as_float(cand);
    int c0 = 0, c1 = 0, c2 = 0, c3 = 0;
#pragma unroll
    for (int i = 0; i < 32; i += 4) {
      c0 += __builtin_popcountll(__ballot(fabsf(mg[i + 0]) < candf));
      c1 += __builtin_popcountll(__ballot(fabsf(mg[i + 1]) < candf));
      c2 += __builtin_popcountll(__ballot(fabsf(mg[i + 2]) < candf));
      c3 += __builtin_popcountll(__ballot(fabsf(mg[i + 3]) < candf));
    }
    if (((c0 + c1) + (c2 + c3)) < 32) T = cand;
  }

  // ---- sum of squares strictly below T; ties filled with midpoint^2 ----
  const float Tf = __uint_as_float(T);
  float ssum = 0.0f;
  int cb = 0;
#pragma unroll
  for (int i = 0; i < 32; ++i) {
    const bool below = fabsf(mg[i]) < Tf;
    cb += __builtin_popcountll(__ballot(below));
    const float m = below ? mg[i] : 0.0f;
    ssum = fmaf(m, m, ssum);
  }
#pragma unroll
  for (int off = 32; off; off >>= 1) ssum += __shfl_xor(ssum, off, 64);

  const float Tmid = __uint_as_float(T + (1u << (LOWBIT - 1)));
  const float noise = (ssum + (float)(32 - cb) * (Tmid * Tmid)) * (1.0f / 32.0f);

  // ---- epilogue: relu(mag - noise) * {cos,sin}(phase) -- register-only,
  // streamed out with nontemporal stores.
  float* orp = out + base;               // channel 0: real
  float* oip = out + base + HALF_PLANE;  // channel 1: imag
#pragma unroll
  for (int j = 0; j < 8; ++j) {
    v4f re, im;
    float s, c, m;

    m = fmaxf(mg[4 * j + 0] - noise, 0.0f);
    __sincosf(ph[4 * j + 0], &s, &c);
    re.x = m * c; im.x = m * s;

    m = fmaxf(mg[4 * j + 1] - noise, 0.0f);
    __sincosf(ph[4 * j + 1], &s, &c);
    re.y = m * c; im.y = m * s;

    m = fmaxf(mg[4 * j + 2] - noise, 0.0f);
    __sincosf(ph[4 * j + 2], &s, &c);
    re.z = m * c; im.z = m * s;

    m = fmaxf(mg[4 * j + 3] - noise, 0.0f);
    __sincosf(ph[4 * j + 3], &s, &c);
    re.w = m * c; im.w = m * s;

    __builtin_nontemporal_store(re, (v4f*)(orp + j * 256 + lane * 4));
    __builtin_nontemporal_store(im, (v4f*)(oip + j * 256 + lane * 4));
  }
}

extern "C" void kernel_launch(void* const* d_in, const int* in_sizes, int n_in,
                              void* d_out, int out_size, void* d_ws, size_t ws_size,
                              hipStream_t stream) {
  const float* x = (const float*)d_in[0];
  float* out = (float*)d_out;
  // n_avg (d_in[1]) is a compile-time constant 32 per the reference.
  const int blocks = NROWS / 4;  // 4 rows (waves) per 256-thread block
  spectral_sub_kernel<<<blocks, 256, 0, stream>>>(x, out);
}